// Round 7
// baseline (161.601 us; speedup 1.0000x reference)
//
#include <hip/hip_runtime.h>

// GCN 2-layer forward. Partition counting-sort CSR build (4 kernels, LDS-only
// atomics), MFMA GEMMs (3-term bf16 split), bf16 feature tables for the
// gather-heavy aggregation. Aggregation inner loops are fixed-trip and fully
// unrolled so the random gathers pipeline (latency-bound -> MLP).

#define F1 64
#define F2 16
#define G 256      // chunk blocks for partition passes
#define HP 256     // partition stride; partition = dst >> 8; npart <= 256 (n <= 65536)

typedef __attribute__((ext_vector_type(8))) short bf16x8;
typedef __attribute__((ext_vector_type(4))) float f32x4;
typedef __attribute__((ext_vector_type(4))) unsigned short u16x4;

// f32 -> bf16 round-to-nearest-even
__device__ inline unsigned short f2bf(float f) {
    unsigned u = __float_as_uint(f);
    return (unsigned short)((u + 0x7FFFu + ((u >> 16) & 1u)) >> 16);
}
__device__ inline float bf2f(unsigned short s) {
    return __uint_as_float(((unsigned)s) << 16);
}

// split 8 f32 into hi/lo bf16 (truncation split: hi exact-high, lo ~2^-17 rel)
__device__ inline void cvt8(const float* v, bf16x8& h, bf16x8& l) {
#pragma unroll
    for (int i = 0; i < 8; ++i) {
        unsigned b = __float_as_uint(v[i]);
        h[i] = (short)(b >> 16);
        float hif = __uint_as_float(b & 0xFFFF0000u);
        float lof = v[i] - hif;
        l[i] = (short)(__float_as_uint(lof) >> 16);
    }
}

// ---------------- CSR build ----------------

// P1: per-chunk histogram over partitions
__global__ __launch_bounds__(256) void k_hist(const int4* __restrict__ dst4,
                                              const int* __restrict__ dst,
                                              int* __restrict__ hist, int e4, int e) {
    __shared__ int hl[HP];
    int tid = threadIdx.x, g = blockIdx.x;
    hl[tid] = 0;
    __syncthreads();
    int chunk = (e4 + G - 1) / G;
    int beg = g * chunk, end = min(e4, beg + chunk);
    for (int i = beg + tid; i < end; i += 256) {
        int4 d = dst4[i];
        atomicAdd(&hl[d.x >> 8], 1);
        atomicAdd(&hl[d.y >> 8], 1);
        atomicAdd(&hl[d.z >> 8], 1);
        atomicAdd(&hl[d.w >> 8], 1);
    }
    if (g == G - 1)
        for (int i = e4 * 4 + tid; i < e; i += 256) atomicAdd(&hl[dst[i] >> 8], 1);
    __syncthreads();
    hist[g * HP + tid] = hl[tid];
}

// P2: per-partition scan over chunks -> local offsets + partition totals
__global__ __launch_bounds__(256) void k_cscan(const int* __restrict__ hist,
                                               int* __restrict__ pgoff,
                                               int* __restrict__ ptotal) {
    __shared__ int s[G];
    int p = blockIdx.x, g = threadIdx.x;
    int v = hist[g * HP + p];
    s[g] = v;
    __syncthreads();
    for (int off = 1; off < G; off <<= 1) {
        int t = (g >= off) ? s[g - off] : 0;
        __syncthreads();
        s[g] += t;
        __syncthreads();
    }
    pgoff[g * HP + p] = s[g] - v;  // chunk-local exclusive
    if (g == G - 1) ptotal[p] = s[g];
}

// P3: scatter edges into partition-grouped packed pairs (block-private cursors)
__global__ __launch_bounds__(256) void k_part(const int4* __restrict__ src4,
                                              const int4* __restrict__ dst4,
                                              const int* __restrict__ src,
                                              const int* __restrict__ dst,
                                              const int* __restrict__ pgoff,
                                              const int* __restrict__ ptotal,
                                              unsigned* __restrict__ pairs,
                                              int e4, int e, int npart) {
    __shared__ int s[HP];
    __shared__ int cur[HP];
    int tid = threadIdx.x, g = blockIdx.x;
    int v = (tid < npart) ? ptotal[tid] : 0;
    s[tid] = v;
    __syncthreads();
    for (int off = 1; off < HP; off <<= 1) {
        int t = (tid >= off) ? s[tid - off] : 0;
        __syncthreads();
        s[tid] += t;
        __syncthreads();
    }
    cur[tid] = (s[tid] - v) + pgoff[g * HP + tid];  // part_base + chunk offset
    __syncthreads();
    int chunk = (e4 + G - 1) / G;
    int beg = g * chunk, end = min(e4, beg + chunk);
    for (int i = beg + tid; i < end; i += 256) {
        int4 s4 = src4[i];
        int4 d4 = dst4[i];
        int pos;
        pos = atomicAdd(&cur[d4.x >> 8], 1); pairs[pos] = ((unsigned)(d4.x & 255) << 16) | (unsigned)s4.x;
        pos = atomicAdd(&cur[d4.y >> 8], 1); pairs[pos] = ((unsigned)(d4.y & 255) << 16) | (unsigned)s4.y;
        pos = atomicAdd(&cur[d4.z >> 8], 1); pairs[pos] = ((unsigned)(d4.z & 255) << 16) | (unsigned)s4.z;
        pos = atomicAdd(&cur[d4.w >> 8], 1); pairs[pos] = ((unsigned)(d4.w & 255) << 16) | (unsigned)s4.w;
    }
    if (g == G - 1)
        for (int i = e4 * 4 + tid; i < e; i += 256) {
            int d = dst[i];
            int pos = atomicAdd(&cur[d >> 8], 1);
            pairs[pos] = ((unsigned)(d & 255) << 16) | (unsigned)src[i];
        }
}

// P4: per-partition bucket sort -> csr; fuses rowstart + dinv
__global__ __launch_bounds__(256) void k_csr(const unsigned* __restrict__ pairs,
                                             const int* __restrict__ ptotal,
                                             int* __restrict__ rowstart,
                                             float* __restrict__ dinv,
                                             int* __restrict__ csr,
                                             int n, int e, int npart) {
    __shared__ int s[HP];
    __shared__ int cnt[256], cur[256];
    __shared__ int wbs, wes;
    int p = blockIdx.x, tid = threadIdx.x;
    int v = (tid < npart) ? ptotal[tid] : 0;
    s[tid] = v;
    __syncthreads();
    for (int off = 1; off < HP; off <<= 1) {
        int t = (tid >= off) ? s[tid - off] : 0;
        __syncthreads();
        s[tid] += t;
        __syncthreads();
    }
    if (tid == p) { wbs = s[tid] - v; wes = s[tid]; }
    cnt[tid] = 0;
    __syncthreads();
    int wbeg = wbs, wend = wes;
    for (int i = wbeg + tid; i < wend; i += 256)
        atomicAdd(&cnt[pairs[i] >> 16], 1);
    __syncthreads();
    int c = cnt[tid];
    s[tid] = c;
    __syncthreads();
    for (int off = 1; off < 256; off <<= 1) {
        int t = (tid >= off) ? s[tid - off] : 0;
        __syncthreads();
        s[tid] += t;
        __syncthreads();
    }
    int rs = wbeg + s[tid] - c;  // exclusive within window
    cur[tid] = rs;
    int node = (p << 8) + tid;
    if (node < n) {
        rowstart[node] = rs;
        dinv[node] = rsqrtf((float)c + 1.0f);  // +1 self loop
    }
    if (p == 0 && tid == 0) rowstart[n] = e;
    __syncthreads();
    for (int i = wbeg + tid; i < wend; i += 256) {
        unsigned u = pairs[i];
        int pos = atomicAdd(&cur[u >> 16], 1);
        csr[pos] = (int)(u & 0xFFFFu);
    }
}

// ---------------- GEMMs (MFMA, 3-term bf16 split) ----------------

// h_bf = bf16(x @ W1)
__global__ __launch_bounds__(256) void k_mgemm1(const float* __restrict__ x,
                                                const float* __restrict__ W1,
                                                unsigned short* __restrict__ h_bf, int n) {
    __shared__ float ws[64 * 65];
    int tid = threadIdx.x;
    for (int i = tid; i < 64 * 64; i += 256) {
        int k = i >> 6, c = i & 63;
        ws[k * 65 + c] = W1[i];
    }
    __syncthreads();
    int lane = tid & 63, wv = tid >> 6;
    int rt = blockIdx.x * 64 + wv * 16;
    int r = lane & 15, g = lane >> 4;
    int row = rt + r;
    int rowc = row < n ? row : n - 1;
    const float* xp = x + (size_t)rowc * F1 + g * 8;
    bf16x8 ah[2], al[2];
#pragma unroll
    for (int kb = 0; kb < 2; ++kb) {
        float v[8];
        *(float4*)&v[0] = *(const float4*)(xp + kb * 32);
        *(float4*)&v[4] = *(const float4*)(xp + kb * 32 + 4);
        cvt8(v, ah[kb], al[kb]);
    }
#pragma unroll
    for (int ct = 0; ct < 4; ++ct) {
        bf16x8 bh[2], bl[2];
#pragma unroll
        for (int kb = 0; kb < 2; ++kb) {
            float v[8];
#pragma unroll
            for (int i = 0; i < 8; ++i)
                v[i] = ws[(kb * 32 + g * 8 + i) * 65 + ct * 16 + r];
            cvt8(v, bh[kb], bl[kb]);
        }
        f32x4 acc = {0.f, 0.f, 0.f, 0.f};
#pragma unroll
        for (int kb = 0; kb < 2; ++kb) {
            acc = __builtin_amdgcn_mfma_f32_16x16x32_bf16(ah[kb], bh[kb], acc, 0, 0, 0);
            acc = __builtin_amdgcn_mfma_f32_16x16x32_bf16(al[kb], bh[kb], acc, 0, 0, 0);
            acc = __builtin_amdgcn_mfma_f32_16x16x32_bf16(ah[kb], bl[kb], acc, 0, 0, 0);
        }
#pragma unroll
        for (int j = 0; j < 4; ++j) {
            int orow = rt + g * 4 + j;
            if (orow < n) h_bf[(size_t)orow * F1 + ct * 16 + r] = f2bf(acc[j]);
        }
    }
}

// h2_bf = bf16( relu(agg1 + b1) @ W2 )
__global__ __launch_bounds__(256) void k_mgemm2(const float* __restrict__ agg1,
                                                const float* __restrict__ b1,
                                                const float* __restrict__ W2,
                                                unsigned short* __restrict__ h2_bf, int n) {
    __shared__ float ws[64 * 17];
    int tid = threadIdx.x;
    for (int i = tid; i < 64 * 16; i += 256) {
        int k = i >> 4, c = i & 15;
        ws[k * 17 + c] = W2[i];
    }
    __syncthreads();
    int lane = tid & 63, wv = tid >> 6;
    int rt = blockIdx.x * 64 + wv * 16;
    int r = lane & 15, g = lane >> 4;
    int row = rt + r;
    int rowc = row < n ? row : n - 1;
    const float* ap = agg1 + (size_t)rowc * F1 + g * 8;
    const float* bp = b1 + g * 8;
    bf16x8 ah[2], al[2];
#pragma unroll
    for (int kb = 0; kb < 2; ++kb) {
        float v[8], b[8];
        *(float4*)&v[0] = *(const float4*)(ap + kb * 32);
        *(float4*)&v[4] = *(const float4*)(ap + kb * 32 + 4);
        *(float4*)&b[0] = *(const float4*)(bp + kb * 32);
        *(float4*)&b[4] = *(const float4*)(bp + kb * 32 + 4);
#pragma unroll
        for (int i = 0; i < 8; ++i) v[i] = fmaxf(v[i] + b[i], 0.f);
        cvt8(v, ah[kb], al[kb]);
    }
    bf16x8 bh[2], bl[2];
#pragma unroll
    for (int kb = 0; kb < 2; ++kb) {
        float v[8];
#pragma unroll
        for (int i = 0; i < 8; ++i)
            v[i] = ws[(kb * 32 + g * 8 + i) * 17 + r];
        cvt8(v, bh[kb], bl[kb]);
    }
    f32x4 acc = {0.f, 0.f, 0.f, 0.f};
#pragma unroll
    for (int kb = 0; kb < 2; ++kb) {
        acc = __builtin_amdgcn_mfma_f32_16x16x32_bf16(ah[kb], bh[kb], acc, 0, 0, 0);
        acc = __builtin_amdgcn_mfma_f32_16x16x32_bf16(al[kb], bh[kb], acc, 0, 0, 0);
        acc = __builtin_amdgcn_mfma_f32_16x16x32_bf16(ah[kb], bl[kb], acc, 0, 0, 0);
    }
#pragma unroll
    for (int j = 0; j < 4; ++j) {
        int orow = rt + g * 4 + j;
        if (orow < n) h2_bf[(size_t)orow * F2 + r] = f2bf(acc[j]);
    }
}

// ---------------- Aggregation (gather, bf16 tables, f32 accumulate) ----------------
// Fixed-trip unrolled inner loops: dead slots have dv=0 (w=0) and idx=0 (cached
// row-0 gather), so masking is free and all loads issue back-to-back.

__global__ __launch_bounds__(256) void k_agg64(const int* __restrict__ rowstart,
                                               const int* __restrict__ csr,
                                               const float* __restrict__ dinv,
                                               const unsigned short* __restrict__ hb,
                                               float* __restrict__ agg, int n) {
    int lane = threadIdx.x & 63, wv = threadIdx.x >> 6;
    int node = blockIdx.x * 4 + wv;
    if (node >= n) return;
    int g = lane >> 4, q = lane & 15;
    float di = dinv[node];
    float4 acc = {0.f, 0.f, 0.f, 0.f};
    int beg = rowstart[node], end = rowstart[node + 1];
    for (int base = beg; base < end; base += 64) {
        int k = base + lane;
        int idx = (k < end) ? csr[k] : 0;
        float dv = (k < end) ? dinv[idx] : 0.0f;
        int m = end - base;  // >0; slots >= m are masked via dv=0
        if (m <= 32) {
#pragma unroll
            for (int i = 0; i < 8; ++i) {
                int slot = i * 4 + g;
                int s = __shfl(idx, slot, 64);
                float w = __shfl(dv, slot, 64);
                u16x4 u = *(const u16x4*)(hb + (size_t)s * F1 + q * 4);
                acc.x = fmaf(w, bf2f(u.x), acc.x);
                acc.y = fmaf(w, bf2f(u.y), acc.y);
                acc.z = fmaf(w, bf2f(u.z), acc.z);
                acc.w = fmaf(w, bf2f(u.w), acc.w);
            }
        } else {
#pragma unroll
            for (int i = 0; i < 16; ++i) {
                int slot = i * 4 + g;
                int s = __shfl(idx, slot, 64);
                float w = __shfl(dv, slot, 64);
                u16x4 u = *(const u16x4*)(hb + (size_t)s * F1 + q * 4);
                acc.x = fmaf(w, bf2f(u.x), acc.x);
                acc.y = fmaf(w, bf2f(u.y), acc.y);
                acc.z = fmaf(w, bf2f(u.z), acc.z);
                acc.w = fmaf(w, bf2f(u.w), acc.w);
            }
        }
    }
#pragma unroll
    for (int off = 16; off <= 32; off <<= 1) {
        acc.x += __shfl_xor(acc.x, off, 64);
        acc.y += __shfl_xor(acc.y, off, 64);
        acc.z += __shfl_xor(acc.z, off, 64);
        acc.w += __shfl_xor(acc.w, off, 64);
    }
    if (g == 0) {
        u16x4 su = *(const u16x4*)(hb + (size_t)node * F1 + q * 4);
        float d2 = di * di;
        float4 o;
        o.x = fmaf(di, acc.x, d2 * bf2f(su.x));
        o.y = fmaf(di, acc.y, d2 * bf2f(su.y));
        o.z = fmaf(di, acc.z, d2 * bf2f(su.z));
        o.w = fmaf(di, acc.w, d2 * bf2f(su.w));
        ((float4*)agg)[(size_t)node * 16 + q] = o;
    }
}

__global__ __launch_bounds__(256) void k_agg16(const int* __restrict__ rowstart,
                                               const int* __restrict__ csr,
                                               const float* __restrict__ dinv,
                                               const unsigned short* __restrict__ h2b,
                                               const float* __restrict__ b2,
                                               float* __restrict__ out, int n) {
    int lane = threadIdx.x & 63, wv = threadIdx.x >> 6;
    int node = blockIdx.x * 4 + wv;
    if (node >= n) return;
    int g = lane >> 2, q = lane & 3;
    float di = dinv[node];
    float4 acc = {0.f, 0.f, 0.f, 0.f};
    int beg = rowstart[node], end = rowstart[node + 1];
    for (int base = beg; base < end; base += 64) {
        int k = base + lane;
        int idx = (k < end) ? csr[k] : 0;
        float dv = (k < end) ? dinv[idx] : 0.0f;
#pragma unroll
        for (int i = 0; i < 4; ++i) {
            int slot = i * 16 + g;
            int s = __shfl(idx, slot, 64);
            float w = __shfl(dv, slot, 64);
            u16x4 u = *(const u16x4*)(h2b + (size_t)s * F2 + q * 4);
            acc.x = fmaf(w, bf2f(u.x), acc.x);
            acc.y = fmaf(w, bf2f(u.y), acc.y);
            acc.z = fmaf(w, bf2f(u.z), acc.z);
            acc.w = fmaf(w, bf2f(u.w), acc.w);
        }
    }
#pragma unroll
    for (int off = 4; off <= 32; off <<= 1) {
        acc.x += __shfl_xor(acc.x, off, 64);
        acc.y += __shfl_xor(acc.y, off, 64);
        acc.z += __shfl_xor(acc.z, off, 64);
        acc.w += __shfl_xor(acc.w, off, 64);
    }
    u16x4 su = *(const u16x4*)(h2b + (size_t)node * F2 + q * 4);
    float4 bv = ((const float4*)b2)[q];
    float d2 = di * di;
    float4 v;
    v.x = fmaf(di, acc.x, fmaf(d2, bf2f(su.x), bv.x));
    v.y = fmaf(di, acc.y, fmaf(d2, bf2f(su.y), bv.y));
    v.z = fmaf(di, acc.z, fmaf(d2, bf2f(su.z), bv.z));
    v.w = fmaf(di, acc.w, fmaf(d2, bf2f(su.w), bv.w));
    float mr = fmaxf(fmaxf(v.x, v.y), fmaxf(v.z, v.w));
    mr = fmaxf(mr, __shfl_xor(mr, 1, 64));
    mr = fmaxf(mr, __shfl_xor(mr, 2, 64));
    float sm = expf(v.x - mr) + expf(v.y - mr) + expf(v.z - mr) + expf(v.w - mr);
    sm += __shfl_xor(sm, 1, 64);
    sm += __shfl_xor(sm, 2, 64);
    float l = mr + logf(sm);
    if (g == 0) {
        float4 o;
        o.x = v.x - l; o.y = v.y - l; o.z = v.z - l; o.w = v.w - l;
        ((float4*)out)[(size_t)node * 4 + q] = o;
    }
}

extern "C" void kernel_launch(void* const* d_in, const int* in_sizes, int n_in,
                              void* d_out, int out_size, void* d_ws, size_t ws_size,
                              hipStream_t stream) {
    const float* x  = (const float*)d_in[0];
    const int*   ei = (const int*)d_in[1];
    const float* W1 = (const float*)d_in[2];
    const float* b1 = (const float*)d_in[3];
    const float* W2 = (const float*)d_in[4];
    const float* b2 = (const float*)d_in[5];
    float* out = (float*)d_out;

    const int n = in_sizes[0] / F1;   // 50000
    const int e = in_sizes[1] / 2;    // 800000
    const int e4 = e >> 2;
    const int* src = ei;
    const int* dst = ei + e;

    const int na = (n + 63) & ~63;
    const int npart = (n + 255) >> 8;  // 196 (<=256 for n<=65536)

    // ws layout (4B units):
    // dinv[na] | rowstart[na+64] | ptotal[256] | csr[e] | h_bf[n*64 u16] | agg1[n*64 f32]
    // CSR-build scratch (hist/pgoff/pairs ~3.7MB) aliases h_bf (dead until k_mgemm1).
    float* dinv     = (float*)d_ws;
    int* rowstart   = (int*)(dinv + na);
    int* ptotal     = rowstart + na + 64;
    int* csr        = ptotal + 256;
    unsigned short* h_bf = (unsigned short*)(csr + ((e + 63) & ~63));
    float* agg1     = (float*)(h_bf + (size_t)n * F1);
    int* hist       = (int*)h_bf;                  // G*HP
    int* pgoff      = hist + G * HP;               // G*HP
    unsigned* pairs = (unsigned*)(pgoff + G * HP); // e
    unsigned short* h2_bf = h_bf;                  // layer-2 reuse

    // ---- CSR build ----
    k_hist <<<G, 256, 0, stream>>>((const int4*)dst, dst, hist, e4, e);
    k_cscan<<<npart, 256, 0, stream>>>(hist, pgoff, ptotal);
    k_part <<<G, 256, 0, stream>>>((const int4*)src, (const int4*)dst, src, dst,
                                   pgoff, ptotal, pairs, e4, e, npart);
    k_csr  <<<npart, 256, 0, stream>>>(pairs, ptotal, rowstart, dinv, csr, n, e, npart);

    // ---- layer 1 ----
    k_mgemm1<<<(n + 63) / 64, 256, 0, stream>>>(x, W1, h_bf, n);
    k_agg64<<<(n + 3) / 4, 256, 0, stream>>>(rowstart, csr, dinv, h_bf, agg1, n);

    // ---- layer 2 ----
    k_mgemm2<<<(n + 63) / 64, 256, 0, stream>>>(agg1, b1, W2, h2_bf, n);
    k_agg16<<<(n + 3) / 4, 256, 0, stream>>>(rowstart, csr, dinv, h2_bf, b2, out, n);
}

// Round 9
// 150.504 us; speedup vs baseline: 1.0737x; 1.0737x over previous
//
#include <hip/hip_runtime.h>

// GCN 2-layer forward. Partition counting-sort CSR build (LDS-only atomics),
// MFMA GEMMs (bf16 split), bf16 feature tables. Round 8: agg64 fuses
// bias1+relu+bf16 (kills the f32 agg1 round-trip); mgemm1 grid-stuffed into
// k_part (independent work overlapped); 7 dispatches.

#define F1 64
#define F2 16
#define G 256      // chunk blocks for partition passes
#define HP 256     // partition stride; partition = dst >> 8; npart <= 256 (n <= 65536)

typedef __attribute__((ext_vector_type(8))) short bf16x8;
typedef __attribute__((ext_vector_type(4))) float f32x4;
typedef __attribute__((ext_vector_type(4))) unsigned short u16x4;

// f32 -> bf16 round-to-nearest-even
__device__ inline unsigned short f2bf(float f) {
    unsigned u = __float_as_uint(f);
    return (unsigned short)((u + 0x7FFFu + ((u >> 16) & 1u)) >> 16);
}
__device__ inline float bf2f(unsigned short s) {
    return __uint_as_float(((unsigned)s) << 16);
}

// split 8 f32 into hi/lo bf16 (truncation split: hi exact-high, lo ~2^-17 rel)
__device__ inline void cvt8(const float* v, bf16x8& h, bf16x8& l) {
#pragma unroll
    for (int i = 0; i < 8; ++i) {
        unsigned b = __float_as_uint(v[i]);
        h[i] = (short)(b >> 16);
        float hif = __uint_as_float(b & 0xFFFF0000u);
        float lof = v[i] - hif;
        l[i] = (short)(__float_as_uint(lof) >> 16);
    }
}

// ---------------- CSR build ----------------

// P1: per-chunk histogram over partitions
__global__ __launch_bounds__(256) void k_hist(const int4* __restrict__ dst4,
                                              const int* __restrict__ dst,
                                              int* __restrict__ hist, int e4, int e) {
    __shared__ int hl[HP];
    int tid = threadIdx.x, g = blockIdx.x;
    hl[tid] = 0;
    __syncthreads();
    int chunk = (e4 + G - 1) / G;
    int beg = g * chunk, end = min(e4, beg + chunk);
    for (int i = beg + tid; i < end; i += 256) {
        int4 d = dst4[i];
        atomicAdd(&hl[d.x >> 8], 1);
        atomicAdd(&hl[d.y >> 8], 1);
        atomicAdd(&hl[d.z >> 8], 1);
        atomicAdd(&hl[d.w >> 8], 1);
    }
    if (g == G - 1)
        for (int i = e4 * 4 + tid; i < e; i += 256) atomicAdd(&hl[dst[i] >> 8], 1);
    __syncthreads();
    hist[g * HP + tid] = hl[tid];
}

// P2: per-partition scan over chunks -> local offsets + partition totals
__global__ __launch_bounds__(256) void k_cscan(const int* __restrict__ hist,
                                               int* __restrict__ pgoff,
                                               int* __restrict__ ptotal) {
    __shared__ int s[G];
    int p = blockIdx.x, g = threadIdx.x;
    int v = hist[g * HP + p];
    s[g] = v;
    __syncthreads();
    for (int off = 1; off < G; off <<= 1) {
        int t = (g >= off) ? s[g - off] : 0;
        __syncthreads();
        s[g] += t;
        __syncthreads();
    }
    pgoff[g * HP + p] = s[g] - v;  // chunk-local exclusive
    if (g == G - 1) ptotal[p] = s[g];
}

// P3 + GEMM1 fused (independent work, block-range branch).
// blocks [0, nb1): h_bf = bf16(x @ W1)   (MFMA, 3-term split)
// blocks [nb1, nb1+G): partition scatter into packed pairs
__global__ __launch_bounds__(256) void k_pm1(const float* __restrict__ x,
                                             const float* __restrict__ W1,
                                             unsigned short* __restrict__ h_bf,
                                             const int4* __restrict__ src4,
                                             const int4* __restrict__ dst4,
                                             const int* __restrict__ src,
                                             const int* __restrict__ dst,
                                             const int* __restrict__ pgoff,
                                             const int* __restrict__ ptotal,
                                             unsigned* __restrict__ pairs,
                                             int e4, int e, int npart,
                                             int n, int nb1) {
    __shared__ float ws[64 * 65];        // mgemm1 branch
    __shared__ int s[HP], cur[HP];       // part branch
    int tid = threadIdx.x;
    if ((int)blockIdx.x < nb1) {
        // ---- mgemm1 ----
        for (int i = tid; i < 64 * 64; i += 256) {
            int k = i >> 6, c = i & 63;
            ws[k * 65 + c] = W1[i];
        }
        __syncthreads();
        int lane = tid & 63, wv = tid >> 6;
        int rt = blockIdx.x * 64 + wv * 16;
        int r = lane & 15, g = lane >> 4;
        int row = rt + r;
        int rowc = row < n ? row : n - 1;
        const float* xp = x + (size_t)rowc * F1 + g * 8;
        bf16x8 ah[2], al[2];
#pragma unroll
        for (int kb = 0; kb < 2; ++kb) {
            float v[8];
            *(float4*)&v[0] = *(const float4*)(xp + kb * 32);
            *(float4*)&v[4] = *(const float4*)(xp + kb * 32 + 4);
            cvt8(v, ah[kb], al[kb]);
        }
#pragma unroll
        for (int ct = 0; ct < 4; ++ct) {
            bf16x8 bh[2], bl[2];
#pragma unroll
            for (int kb = 0; kb < 2; ++kb) {
                float v[8];
#pragma unroll
                for (int i = 0; i < 8; ++i)
                    v[i] = ws[(kb * 32 + g * 8 + i) * 65 + ct * 16 + r];
                cvt8(v, bh[kb], bl[kb]);
            }
            f32x4 acc = {0.f, 0.f, 0.f, 0.f};
#pragma unroll
            for (int kb = 0; kb < 2; ++kb) {
                acc = __builtin_amdgcn_mfma_f32_16x16x32_bf16(ah[kb], bh[kb], acc, 0, 0, 0);
                acc = __builtin_amdgcn_mfma_f32_16x16x32_bf16(al[kb], bh[kb], acc, 0, 0, 0);
                acc = __builtin_amdgcn_mfma_f32_16x16x32_bf16(ah[kb], bl[kb], acc, 0, 0, 0);
            }
#pragma unroll
            for (int j = 0; j < 4; ++j) {
                int orow = rt + g * 4 + j;
                if (orow < n) h_bf[(size_t)orow * F1 + ct * 16 + r] = f2bf(acc[j]);
            }
        }
    } else {
        // ---- part ----
        int g = blockIdx.x - nb1;
        int v = (tid < npart) ? ptotal[tid] : 0;
        s[tid] = v;
        __syncthreads();
        for (int off = 1; off < HP; off <<= 1) {
            int t = (tid >= off) ? s[tid - off] : 0;
            __syncthreads();
            s[tid] += t;
            __syncthreads();
        }
        cur[tid] = (s[tid] - v) + pgoff[g * HP + tid];  // part_base + chunk offset
        __syncthreads();
        int chunk = (e4 + G - 1) / G;
        int beg = g * chunk, end = min(e4, beg + chunk);
        for (int i = beg + tid; i < end; i += 256) {
            int4 s4 = src4[i];
            int4 d4 = dst4[i];
            int pos;
            pos = atomicAdd(&cur[d4.x >> 8], 1); pairs[pos] = ((unsigned)(d4.x & 255) << 16) | (unsigned)s4.x;
            pos = atomicAdd(&cur[d4.y >> 8], 1); pairs[pos] = ((unsigned)(d4.y & 255) << 16) | (unsigned)s4.y;
            pos = atomicAdd(&cur[d4.z >> 8], 1); pairs[pos] = ((unsigned)(d4.z & 255) << 16) | (unsigned)s4.z;
            pos = atomicAdd(&cur[d4.w >> 8], 1); pairs[pos] = ((unsigned)(d4.w & 255) << 16) | (unsigned)s4.w;
        }
        if (g == G - 1)
            for (int i = e4 * 4 + tid; i < e; i += 256) {
                int d = dst[i];
                int pos = atomicAdd(&cur[d >> 8], 1);
                pairs[pos] = ((unsigned)(d & 255) << 16) | (unsigned)src[i];
            }
    }
}

// P4: per-partition bucket sort -> csr; fuses rowstart + dinv
__global__ __launch_bounds__(256) void k_csr(const unsigned* __restrict__ pairs,
                                             const int* __restrict__ ptotal,
                                             int* __restrict__ rowstart,
                                             float* __restrict__ dinv,
                                             int* __restrict__ csr,
                                             int n, int e, int npart) {
    __shared__ int s[HP];
    __shared__ int cnt[256], cur[256];
    __shared__ int wbs, wes;
    int p = blockIdx.x, tid = threadIdx.x;
    int v = (tid < npart) ? ptotal[tid] : 0;
    s[tid] = v;
    __syncthreads();
    for (int off = 1; off < HP; off <<= 1) {
        int t = (tid >= off) ? s[tid - off] : 0;
        __syncthreads();
        s[tid] += t;
        __syncthreads();
    }
    if (tid == p) { wbs = s[tid] - v; wes = s[tid]; }
    cnt[tid] = 0;
    __syncthreads();
    int wbeg = wbs, wend = wes;
    for (int i = wbeg + tid; i < wend; i += 256)
        atomicAdd(&cnt[pairs[i] >> 16], 1);
    __syncthreads();
    int c = cnt[tid];
    s[tid] = c;
    __syncthreads();
    for (int off = 1; off < 256; off <<= 1) {
        int t = (tid >= off) ? s[tid - off] : 0;
        __syncthreads();
        s[tid] += t;
        __syncthreads();
    }
    int rs = wbeg + s[tid] - c;  // exclusive within window
    cur[tid] = rs;
    int node = (p << 8) + tid;
    if (node < n) {
        rowstart[node] = rs;
        dinv[node] = rsqrtf((float)c + 1.0f);  // +1 self loop
    }
    if (p == 0 && tid == 0) rowstart[n] = e;
    __syncthreads();
    for (int i = wbeg + tid; i < wend; i += 256) {
        unsigned u = pairs[i];
        int pos = atomicAdd(&cur[u >> 16], 1);
        csr[pos] = (int)(u & 0xFFFFu);
    }
}

// h2_bf = bf16( a1b @ W2 ); A is pre-activated bf16 (bias1+relu fused upstream)
__global__ __launch_bounds__(256) void k_mgemm2(const unsigned short* __restrict__ a1b,
                                                const float* __restrict__ W2,
                                                unsigned short* __restrict__ h2_bf, int n) {
    __shared__ float ws[64 * 17];
    int tid = threadIdx.x;
    for (int i = tid; i < 64 * 16; i += 256) {
        int k = i >> 4, c = i & 15;
        ws[k * 17 + c] = W2[i];
    }
    __syncthreads();
    int lane = tid & 63, wv = tid >> 6;
    int rt = blockIdx.x * 64 + wv * 16;
    int r = lane & 15, g = lane >> 4;
    int row = rt + r;
    int rowc = row < n ? row : n - 1;
    const unsigned short* ap = a1b + (size_t)rowc * F1 + g * 8;
    bf16x8 ah[2];
    ah[0] = *(const bf16x8*)(ap);
    ah[1] = *(const bf16x8*)(ap + 32);
    bf16x8 bh[2], bl[2];
#pragma unroll
    for (int kb = 0; kb < 2; ++kb) {
        float v[8];
#pragma unroll
        for (int i = 0; i < 8; ++i)
            v[i] = ws[(kb * 32 + g * 8 + i) * 17 + r];
        cvt8(v, bh[kb], bl[kb]);
    }
    f32x4 acc = {0.f, 0.f, 0.f, 0.f};
#pragma unroll
    for (int kb = 0; kb < 2; ++kb) {
        acc = __builtin_amdgcn_mfma_f32_16x16x32_bf16(ah[kb], bh[kb], acc, 0, 0, 0);
        acc = __builtin_amdgcn_mfma_f32_16x16x32_bf16(ah[kb], bl[kb], acc, 0, 0, 0);
    }
#pragma unroll
    for (int j = 0; j < 4; ++j) {
        int orow = rt + g * 4 + j;
        if (orow < n) h2_bf[(size_t)orow * F2 + r] = f2bf(acc[j]);
    }
}

// ---------------- Aggregation (gather, bf16 tables, f32 accumulate) ----------------

// layer-1 aggregation; epilogue fuses +b1, relu, bf16 store (A-operand of gemm2)
__global__ __launch_bounds__(256) void k_agg64(const int* __restrict__ rowstart,
                                               const int* __restrict__ csr,
                                               const float* __restrict__ dinv,
                                               const unsigned short* __restrict__ hb,
                                               const float* __restrict__ b1,
                                               unsigned short* __restrict__ a1b, int n) {
    int lane = threadIdx.x & 63, wv = threadIdx.x >> 6;
    int node = blockIdx.x * 4 + wv;
    if (node >= n) return;
    int g = lane >> 4, q = lane & 15;
    float di = dinv[node];
    float4 acc = {0.f, 0.f, 0.f, 0.f};
    int beg = rowstart[node], end = rowstart[node + 1];
    for (int base = beg; base < end; base += 64) {
        int k = base + lane;
        int idx = (k < end) ? csr[k] : 0;
        float dv = (k < end) ? dinv[idx] : 0.0f;
        int m = end - base;  // >0; slots >= m are masked via dv=0
        if (m <= 32) {
#pragma unroll
            for (int i = 0; i < 8; ++i) {
                int slot = i * 4 + g;
                int s = __shfl(idx, slot, 64);
                float w = __shfl(dv, slot, 64);
                u16x4 u = *(const u16x4*)(hb + (size_t)s * F1 + q * 4);
                acc.x = fmaf(w, bf2f(u.x), acc.x);
                acc.y = fmaf(w, bf2f(u.y), acc.y);
                acc.z = fmaf(w, bf2f(u.z), acc.z);
                acc.w = fmaf(w, bf2f(u.w), acc.w);
            }
        } else {
#pragma unroll
            for (int i = 0; i < 16; ++i) {
                int slot = i * 4 + g;
                int s = __shfl(idx, slot, 64);
                float w = __shfl(dv, slot, 64);
                u16x4 u = *(const u16x4*)(hb + (size_t)s * F1 + q * 4);
                acc.x = fmaf(w, bf2f(u.x), acc.x);
                acc.y = fmaf(w, bf2f(u.y), acc.y);
                acc.z = fmaf(w, bf2f(u.z), acc.z);
                acc.w = fmaf(w, bf2f(u.w), acc.w);
            }
        }
    }
#pragma unroll
    for (int off = 16; off <= 32; off <<= 1) {
        acc.x += __shfl_xor(acc.x, off, 64);
        acc.y += __shfl_xor(acc.y, off, 64);
        acc.z += __shfl_xor(acc.z, off, 64);
        acc.w += __shfl_xor(acc.w, off, 64);
    }
    if (g == 0) {
        u16x4 su = *(const u16x4*)(hb + (size_t)node * F1 + q * 4);
        float4 bv = ((const float4*)b1)[q];
        float d2 = di * di;
        float4 o;
        o.x = fmaxf(fmaf(di, acc.x, fmaf(d2, bf2f(su.x), bv.x)), 0.f);
        o.y = fmaxf(fmaf(di, acc.y, fmaf(d2, bf2f(su.y), bv.y)), 0.f);
        o.z = fmaxf(fmaf(di, acc.z, fmaf(d2, bf2f(su.z), bv.z)), 0.f);
        o.w = fmaxf(fmaf(di, acc.w, fmaf(d2, bf2f(su.w), bv.w)), 0.f);
        u16x4 rv;
        rv.x = f2bf(o.x); rv.y = f2bf(o.y); rv.z = f2bf(o.z); rv.w = f2bf(o.w);
        *(u16x4*)(a1b + (size_t)node * F1 + q * 4) = rv;
    }
}

__global__ __launch_bounds__(256) void k_agg16(const int* __restrict__ rowstart,
                                               const int* __restrict__ csr,
                                               const float* __restrict__ dinv,
                                               const unsigned short* __restrict__ h2b,
                                               const float* __restrict__ b2,
                                               float* __restrict__ out, int n) {
    int lane = threadIdx.x & 63, wv = threadIdx.x >> 6;
    int node = blockIdx.x * 4 + wv;
    if (node >= n) return;
    int g = lane >> 2, q = lane & 3;
    float di = dinv[node];
    float4 acc = {0.f, 0.f, 0.f, 0.f};
    int beg = rowstart[node], end = rowstart[node + 1];
    for (int base = beg; base < end; base += 64) {
        int k = base + lane;
        int idx = (k < end) ? csr[k] : 0;
        float dv = (k < end) ? dinv[idx] : 0.0f;
#pragma unroll
        for (int i = 0; i < 4; ++i) {
            int slot = i * 16 + g;
            int s = __shfl(idx, slot, 64);
            float w = __shfl(dv, slot, 64);
            u16x4 u = *(const u16x4*)(h2b + (size_t)s * F2 + q * 4);
            acc.x = fmaf(w, bf2f(u.x), acc.x);
            acc.y = fmaf(w, bf2f(u.y), acc.y);
            acc.z = fmaf(w, bf2f(u.z), acc.z);
            acc.w = fmaf(w, bf2f(u.w), acc.w);
        }
    }
#pragma unroll
    for (int off = 4; off <= 32; off <<= 1) {
        acc.x += __shfl_xor(acc.x, off, 64);
        acc.y += __shfl_xor(acc.y, off, 64);
        acc.z += __shfl_xor(acc.z, off, 64);
        acc.w += __shfl_xor(acc.w, off, 64);
    }
    u16x4 su = *(const u16x4*)(h2b + (size_t)node * F2 + q * 4);
    float4 bv = ((const float4*)b2)[q];
    float d2 = di * di;
    float4 v;
    v.x = fmaf(di, acc.x, fmaf(d2, bf2f(su.x), bv.x));
    v.y = fmaf(di, acc.y, fmaf(d2, bf2f(su.y), bv.y));
    v.z = fmaf(di, acc.z, fmaf(d2, bf2f(su.z), bv.z));
    v.w = fmaf(di, acc.w, fmaf(d2, bf2f(su.w), bv.w));
    float mr = fmaxf(fmaxf(v.x, v.y), fmaxf(v.z, v.w));
    mr = fmaxf(mr, __shfl_xor(mr, 1, 64));
    mr = fmaxf(mr, __shfl_xor(mr, 2, 64));
    float sm = expf(v.x - mr) + expf(v.y - mr) + expf(v.z - mr) + expf(v.w - mr);
    sm += __shfl_xor(sm, 1, 64);
    sm += __shfl_xor(sm, 2, 64);
    float l = mr + logf(sm);
    if (g == 0) {
        float4 o;
        o.x = v.x - l; o.y = v.y - l; o.z = v.z - l; o.w = v.w - l;
        ((float4*)out)[(size_t)node * 4 + q] = o;
    }
}

extern "C" void kernel_launch(void* const* d_in, const int* in_sizes, int n_in,
                              void* d_out, int out_size, void* d_ws, size_t ws_size,
                              hipStream_t stream) {
    const float* x  = (const float*)d_in[0];
    const int*   ei = (const int*)d_in[1];
    const float* W1 = (const float*)d_in[2];
    const float* b1 = (const float*)d_in[3];
    const float* W2 = (const float*)d_in[4];
    const float* b2 = (const float*)d_in[5];
    float* out = (float*)d_out;

    const int n = in_sizes[0] / F1;   // 50000
    const int e = in_sizes[1] / 2;    // 800000
    const int e4 = e >> 2;
    const int* src = ei;
    const int* dst = ei + e;

    const int na = (n + 63) & ~63;
    const int npart = (n + 255) >> 8;  // 196 (<=256 for n<=65536)
    const int nb1 = (n + 63) / 64;     // mgemm1 blocks (782)

    // ws layout (4B units), all regions disjoint (scratch no longer aliases h_bf
    // because mgemm1 runs concurrently with k_part):
    // dinv[na] | rowstart[na+64] | ptotal[256] | csr[e] | h_bf[n*64 u16]
    // | a1b[n*64 u16] | hist[G*HP] | pgoff[G*HP] | pairs[e]
    float* dinv     = (float*)d_ws;
    int* rowstart   = (int*)(dinv + na);
    int* ptotal     = rowstart + na + 64;
    int* csr        = ptotal + 256;
    unsigned short* h_bf = (unsigned short*)(csr + ((e + 63) & ~63));
    unsigned short* a1b  = h_bf + (size_t)n * F1;
    int* hist       = (int*)(a1b + (size_t)n * F1);
    int* pgoff      = hist + G * HP;
    unsigned* pairs = (unsigned*)(pgoff + G * HP);
    unsigned short* h2_bf = h_bf;  // layer-2 reuse (h_bf dead after agg64)

    // ---- CSR build + layer-1 GEMM (stuffed) ----
    k_hist <<<G, 256, 0, stream>>>((const int4*)dst, dst, hist, e4, e);
    k_cscan<<<npart, 256, 0, stream>>>(hist, pgoff, ptotal);
    k_pm1  <<<nb1 + G, 256, 0, stream>>>(x, W1, h_bf,
                                         (const int4*)src, (const int4*)dst, src, dst,
                                         pgoff, ptotal, pairs, e4, e, npart, n, nb1);
    k_csr  <<<npart, 256, 0, stream>>>(pairs, ptotal, rowstart, dinv, csr, n, e, npart);

    // ---- layer 1 aggregation (fused bias1+relu+bf16) ----
    k_agg64<<<(n + 3) / 4, 256, 0, stream>>>(rowstart, csr, dinv, h_bf, b1, a1b, n);

    // ---- layer 2 ----
    k_mgemm2<<<(n + 63) / 64, 256, 0, stream>>>(a1b, W2, h2_bf, n);
    k_agg16<<<(n + 3) / 4, 256, 0, stream>>>(rowstart, csr, dinv, h2_bf, b2, out, n);
}